// Round 9
// baseline (203.194 us; speedup 1.0000x reference)
//
#include <hip/hip_runtime.h>
#include <hip/hip_bf16.h>

#define B_  16
#define NQ_ 512
#define NK_ 1024
#define CQ_ 128
#define H_  8
#define D_  64
#define HD_ 512   // H*D

typedef __attribute__((ext_vector_type(8))) short short8;
typedef __attribute__((ext_vector_type(4))) float floatx4;

__device__ __forceinline__ short f2bf(float f) {
    union { float f; unsigned u; } x; x.f = f;
    unsigned r = (x.u + 0x7fffu + ((x.u >> 16) & 1u)) >> 16;  // RNE
    return (short)r;
}
__device__ __forceinline__ int f2bf_pk(float a, float b) {   // packed RNE (v_cvt_pk_bf16_f32)
    __hip_bfloat162 h = __float22bfloat162_rn(make_float2(a, b));
    int r; __builtin_memcpy(&r, &h, 4); return r;
}
__device__ __forceinline__ short8 pack8(float4 a, float4 b) {
    union { int4 i; short8 s; } u;
    u.i = make_int4(f2bf_pk(a.x, a.y), f2bf_pk(a.z, a.w),
                    f2bf_pk(b.x, b.y), f2bf_pk(b.z, b.w));
    return u.s;
}
__device__ __forceinline__ int2 packi2(floatx4 a) {
    return make_int2(f2bf_pk(a[0], a[1]), f2bf_pk(a[2], a[3]));
}

// ---- Stage 0 (prep): W[128][512] fp32 -> Wt[512][128] bf16 (x3), qscale
// folded into wqt and bqs so the fused kernel works in exp2 domain directly.
__global__ void prep_kernel(const float* __restrict__ W0, const float* __restrict__ W1,
                            const float* __restrict__ W2, short* __restrict__ T0,
                            short* __restrict__ T1, short* __restrict__ T2,
                            const float* __restrict__ bq, float* __restrict__ bqs,
                            float qscale) {
    int gi = blockIdx.x * blockDim.x + threadIdx.x;   // 0..197119
    if (gi < 196608) {
        int sel = gi >> 16;
        int idx = gi & 65535;                         // = n*128 + k
        const float* W = sel == 0 ? W0 : (sel == 1 ? W1 : W2);
        short* T = sel == 0 ? T0 : (sel == 1 ? T1 : T2);
        float s = sel == 0 ? qscale : 1.0f;
        int n = idx >> 7, k = idx & 127;
        T[idx] = f2bf(W[k * HD_ + n] * s);
        return;
    }
    int j = gi - 196608;
    if (j < HD_) bqs[j] = bq[j] * qscale;
}

// ---- Fused projection + flash attention ----
// grid 512 = (qquarter bits7-8, bh bits0-6), 256 threads (4 waves).
// Waves 0-1 project K (2 key-tiles each), waves 2-3 project V, into
// double-buffered swizzled LDS; one barrier per 64-key chunk; all waves run
// S^T attention (fixed-max exp2 softmax, swapped-PV O^T epilogue) on 32
// q-rows each. Role weight fragments held in registers across the loop.
__global__ __launch_bounds__(256, 2) void fused_kernel(
    const float* __restrict__ query, const float* __restrict__ key_,
    const float* __restrict__ cmask,
    const short* __restrict__ wqt, const short* __restrict__ wkt,
    const short* __restrict__ wvt,
    const float* __restrict__ bqs, const float* __restrict__ bk,
    const float* __restrict__ bv, float* __restrict__ out)
{
    __shared__ __align__(16) short ksh[2][64 * 64];   // [key][d], swizzled
    __shared__ __align__(16) short vsh[2][64 * 64];   // [d][key], swizzled
    __shared__ __align__(16) short psh[128 * 64];     // [q][*], swizzled, wave-private rows

    const int tid = threadIdx.x;
    const int w = tid >> 6, lane = tid & 63;
    const int l15 = lane & 15, quad = lane >> 4;

    const int bx   = blockIdx.x;
    const int bh_i = bx & 127;            // bh%8 tracks dispatch%8 -> XCD locality
    const int qq   = bx >> 7;             // 0..3 (128 q-rows each)
    const int h    = bh_i & 7;
    const int b    = bh_i >> 3;

    const float* xkey = key_ + (size_t)b * NK_ * CQ_;
    const float* mk   = cmask + (size_t)b * NK_;

    const int kv  = w >> 1;               // 0: K-projector, 1: V-projector
    const int sub = w & 1;                // which pair of key-tiles
    const short* Wkv = kv ? wvt : wkt;

    // --- Phase A: Q projection (swapped: D[m=d][n=q]), via psh round-trip ---
    short8 qa[2][2];
    {
        short8 waf[4][4];
        #pragma unroll
        for (int dt = 0; dt < 4; ++dt)
            #pragma unroll
            for (int kt = 0; kt < 4; ++kt)
                waf[dt][kt] = *(const short8*)(wqt + (size_t)(h * 64 + dt * 16 + l15) * CQ_ + kt * 32 + quad * 8);
        const int qr0 = qq * 128 + w * 32;
        #pragma unroll
        for (int g = 0; g < 2; ++g) {
            const float* qrow = query + ((size_t)b * NQ_ + qr0 + g * 16 + l15) * CQ_;
            short8 bqf[4];
            #pragma unroll
            for (int kt = 0; kt < 4; ++kt)
                bqf[kt] = pack8(*(const float4*)(qrow + kt * 32 + quad * 8),
                                *(const float4*)(qrow + kt * 32 + quad * 8 + 4));
            const int prow = w * 32 + g * 16 + l15;
            #pragma unroll
            for (int dt = 0; dt < 4; ++dt) {
                float4 bi = *(const float4*)(bqs + h * 64 + dt * 16 + quad * 4);
                floatx4 a = {bi.x, bi.y, bi.z, bi.w};
                #pragma unroll
                for (int kt = 0; kt < 4; ++kt)
                    a = __builtin_amdgcn_mfma_f32_16x16x32_bf16(waf[dt][kt], bqf[kt], a, 0, 0, 0);
                const int c16 = (dt * 2 + (quad >> 1)) ^ (prow & 7);
                *(int2*)&psh[prow * 64 + c16 * 8 + (quad & 1) * 4] = packi2(a);
            }
            qa[g][0] = *(const short8*)&psh[prow * 64 + ((quad    ) ^ (prow & 7)) * 8];
            qa[g][1] = *(const short8*)&psh[prow * 64 + ((4 + quad) ^ (prow & 7)) * 8];
        }
    }

    // --- role weights (held in registers across the K-loop) + role bias ---
    short8 wf[4][4];
    #pragma unroll
    for (int dt = 0; dt < 4; ++dt)
        #pragma unroll
        for (int kt = 0; kt < 4; ++kt)
            wf[dt][kt] = *(const short8*)(Wkv + (size_t)(h * 64 + dt * 16 + l15) * CQ_ + kt * 32 + quad * 8);
    float4 bk4[4];
    float  bv4[4];
    #pragma unroll
    for (int dt = 0; dt < 4; ++dt) {
        if (kv == 0) bk4[dt] = *(const float4*)(bk + h * 64 + dt * 16 + quad * 4);
        else         bv4[dt] = bv[h * 64 + dt * 16 + l15];
    }

    auto load_x2 = [&](int kbase, short8 xf[2][4]) {
        #pragma unroll
        for (int j = 0; j < 2; ++j) {
            const int nt = sub * 2 + j;
            const float* krow = xkey + (size_t)(kbase + nt * 16 + l15) * CQ_;
            #pragma unroll
            for (int kt = 0; kt < 4; ++kt)
                xf[j][kt] = pack8(*(const float4*)(krow + kt * 32 + quad * 8),
                                  *(const float4*)(krow + kt * 32 + quad * 8 + 4));
        }
    };
    auto proj_write = [&](short8 xf[2][4], int bufi) {
        #pragma unroll
        for (int j = 0; j < 2; ++j) {
            const int nt = sub * 2 + j;
            if (kv == 0) {     // K: D[m=d][n=key] -> ksh[key][d]
                #pragma unroll
                for (int dt = 0; dt < 4; ++dt) {
                    floatx4 a = {bk4[dt].x, bk4[dt].y, bk4[dt].z, bk4[dt].w};
                    #pragma unroll
                    for (int kt = 0; kt < 4; ++kt)
                        a = __builtin_amdgcn_mfma_f32_16x16x32_bf16(wf[dt][kt], xf[j][kt], a, 0, 0, 0);
                    const int r = nt * 16 + l15;
                    const int c16 = (dt * 2 + (quad >> 1)) ^ (r & 7);
                    *(int2*)&ksh[bufi][r * 64 + c16 * 8 + (quad & 1) * 4] = packi2(a);
                }
            } else {           // V: D[m=key][n=d] -> vsh[d][key]
                #pragma unroll
                for (int dt = 0; dt < 4; ++dt) {
                    floatx4 a = {bv4[dt], bv4[dt], bv4[dt], bv4[dt]};
                    #pragma unroll
                    for (int kt = 0; kt < 4; ++kt)
                        a = __builtin_amdgcn_mfma_f32_16x16x32_bf16(xf[j][kt], wf[dt][kt], a, 0, 0, 0);
                    const int r = dt * 16 + l15;
                    const int c16 = (nt * 2 + (quad >> 1)) ^ (r & 7);
                    *(int2*)&vsh[bufi][r * 64 + c16 * 8 + (quad & 1) * 4] = packi2(a);
                }
            }
        }
    };

    float l_lane[2] = {0.f, 0.f};
    floatx4 o_acc[2][4];
    #pragma unroll
    for (int g = 0; g < 2; ++g)
        #pragma unroll
        for (int dt = 0; dt < 4; ++dt) o_acc[g][dt] = (floatx4){0.f, 0.f, 0.f, 0.f};

    // prologue: project chunk 0
    {
        short8 xf0[2][4];
        load_x2(0, xf0);
        proj_write(xf0, 0);
    }
    __syncthreads();

    for (int t = 0; t < 16; ++t) {
        const int cur = t & 1;
        const int kbase = t * 64;

        // next chunk's X loads issued before attention (latency overlapped)
        short8 xfn[2][4];
        if (t < 15) load_x2(kbase + 64, xfn);

        float4 m4[4];
        #pragma unroll
        for (int n2 = 0; n2 < 4; ++n2)
            m4[n2] = *(const float4*)(mk + kbase + n2 * 16 + quad * 4);

        // K A-frags [m=key][k=d], V A-frags [m=d][k=key] (swizzled reads)
        short8 ka[4][2];
        #pragma unroll
        for (int n2 = 0; n2 < 4; ++n2) {
            const int r = n2 * 16 + l15;
            ka[n2][0] = *(const short8*)&ksh[cur][r * 64 + ((quad    ) ^ (r & 7)) * 8];
            ka[n2][1] = *(const short8*)&ksh[cur][r * 64 + ((4 + quad) ^ (r & 7)) * 8];
        }
        short8 vf[2][4];
        #pragma unroll
        for (int dt = 0; dt < 4; ++dt) {
            const int r = dt * 16 + l15;
            vf[0][dt] = *(const short8*)&vsh[cur][r * 64 + ((quad    ) ^ (r & 7)) * 8];
            vf[1][dt] = *(const short8*)&vsh[cur][r * 64 + ((4 + quad) ^ (r & 7)) * 8];
        }

        #pragma unroll
        for (int g = 0; g < 2; ++g) {
            floatx4 st[4];
            #pragma unroll
            for (int n2 = 0; n2 < 4; ++n2) {
                floatx4 a = {0.f, 0.f, 0.f, 0.f};
                a = __builtin_amdgcn_mfma_f32_16x16x32_bf16(ka[n2][1], qa[g][1], a, 0, 0, 0);
                a = __builtin_amdgcn_mfma_f32_16x16x32_bf16(ka[n2][0], qa[g][0], a, 0, 0, 0);
                st[n2] = a;
            }
            const int prow = w * 32 + g * 16 + l15;
            float psum = 0.f;
            #pragma unroll
            for (int n2 = 0; n2 < 4; ++n2) {
                float p0 = m4[n2].x * __builtin_amdgcn_exp2f(st[n2][0]);
                float p1 = m4[n2].y * __builtin_amdgcn_exp2f(st[n2][1]);
                float p2 = m4[n2].z * __builtin_amdgcn_exp2f(st[n2][2]);
                float p3 = m4[n2].w * __builtin_amdgcn_exp2f(st[n2][3]);
                psum += (p0 + p1) + (p2 + p3);
                const int c16 = (2 * n2 + (quad >> 1)) ^ (prow & 7);
                *(int2*)&psh[prow * 64 + c16 * 8 + (quad & 1) * 4] =
                    make_int2(f2bf_pk(p0, p1), f2bf_pk(p2, p3));
            }
            l_lane[g] += psum;
            // O^T += V^T·P^T (same-wave psh write->read; ds ordering suffices)
            #pragma unroll
            for (int kt = 0; kt < 2; ++kt) {
                short8 pa = *(const short8*)&psh[prow * 64 + ((kt * 4 + quad) ^ (prow & 7)) * 8];
                #pragma unroll
                for (int dt = 0; dt < 4; ++dt)
                    o_acc[g][dt] = __builtin_amdgcn_mfma_f32_16x16x32_bf16(vf[kt][dt], pa, o_acc[g][dt], 0, 0, 0);
            }
        }

        // project next chunk into the other buffer
        if (t < 15) proj_write(xfn, cur ^ 1);
        __syncthreads();
    }

    // epilogue: O^T layout => q=l15, d=dt*16+quad*4+i; float4 stores
    #pragma unroll
    for (int g = 0; g < 2; ++g) {
        float ls = l_lane[g];
        ls += __shfl_xor(ls, 16);
        ls += __shfl_xor(ls, 32);
        const float linv = 1.0f / ls;
        const int qr = qq * 128 + w * 32 + g * 16 + l15;
        float* orow = out + ((size_t)b * NQ_ + qr) * HD_ + h * D_;
        #pragma unroll
        for (int dt = 0; dt < 4; ++dt) {
            float4 v = make_float4(o_acc[g][dt][0] * linv, o_acc[g][dt][1] * linv,
                                   o_acc[g][dt][2] * linv, o_acc[g][dt][3] * linv);
            *(float4*)(orow + dt * 16 + quad * 4) = v;
        }
    }
}

extern "C" void kernel_launch(void* const* d_in, const int* in_sizes, int n_in,
                              void* d_out, int out_size, void* d_ws, size_t ws_size,
                              hipStream_t stream) {
    const float* query = (const float*)d_in[0];
    const float* key   = (const float*)d_in[1];
    const float* cmask = (const float*)d_in[2];
    const float* Wq    = (const float*)d_in[3];
    const float* bq    = (const float*)d_in[4];
    const float* Wk    = (const float*)d_in[5];
    const float* bk    = (const float*)d_in[6];
    const float* Wv    = (const float*)d_in[7];
    const float* bv    = (const float*)d_in[8];
    float* out = (float*)d_out;

    char* ws = (char*)d_ws;
    short* wqt = (short*)(ws);                    // 128 KB each (512*128 bf16)
    short* wkt = (short*)(ws + 131072);
    short* wvt = (short*)(ws + 131072 * 2);
    float* bqs = (float*)(ws + 131072 * 3);       // 2 KB

    const float qscale = 0.125f * 1.44269504f;    // 1/sqrt(64) * log2(e)
    prep_kernel<<<dim3(771), dim3(256), 0, stream>>>(
        Wq, Wk, Wv, wqt, wkt, wvt, bq, bqs, qscale);

    fused_kernel<<<dim3(512), dim3(256), 0, stream>>>(
        query, key, cmask, wqt, wkt, wvt, bqs, bk, bv, out);
}

// Round 10
// 147.648 us; speedup vs baseline: 1.3762x; 1.3762x over previous
//
#include <hip/hip_runtime.h>
#include <hip/hip_bf16.h>

#define B_  16
#define NQ_ 512
#define NK_ 1024
#define CQ_ 128
#define H_  8
#define D_  64
#define HD_ 512   // H*D

typedef __attribute__((ext_vector_type(8))) short short8;
typedef __attribute__((ext_vector_type(4))) float floatx4;

__device__ __forceinline__ short f2bf(float f) {
    union { float f; unsigned u; } x; x.f = f;
    unsigned r = (x.u + 0x7fffu + ((x.u >> 16) & 1u)) >> 16;  // RNE
    return (short)r;
}
__device__ __forceinline__ int f2bf_pk(float a, float b) {   // packed RNE (v_cvt_pk_bf16_f32)
    __hip_bfloat162 h = __float22bfloat162_rn(make_float2(a, b));
    int r; __builtin_memcpy(&r, &h, 4); return r;
}
__device__ __forceinline__ short8 pack8(float4 a, float4 b) {
    union { int4 i; short8 s; } u;
    u.i = make_int4(f2bf_pk(a.x, a.y), f2bf_pk(a.z, a.w),
                    f2bf_pk(b.x, b.y), f2bf_pk(b.z, b.w));
    return u.s;
}
__device__ __forceinline__ int2 packi2(floatx4 a) {
    return make_int2(f2bf_pk(a[0], a[1]), f2bf_pk(a[2], a[3]));
}
// async global->LDS, 16B per lane; LDS dest = uniform base + lane*16
__device__ __forceinline__ void async16(const short* g, short* l) {
    __builtin_amdgcn_global_load_lds(
        (const __attribute__((address_space(1))) void*)g,
        (__attribute__((address_space(3))) void*)l, 16, 0, 0);
}

// ---- Stage 0 (prep): W[128][512] fp32 -> Wt[512][128] bf16 (x3); qscale
// folded into wqt and bqs so attention works in exp2 domain directly.
__global__ void prep_kernel(const float* __restrict__ W0, const float* __restrict__ W1,
                            const float* __restrict__ W2, short* __restrict__ T0,
                            short* __restrict__ T1, short* __restrict__ T2,
                            const float* __restrict__ bq, float* __restrict__ bqs,
                            float qscale) {
    int gi = blockIdx.x * blockDim.x + threadIdx.x;   // 0..197119
    if (gi < 196608) {
        int sel = gi >> 16;
        int idx = gi & 65535;                         // = n*128 + k
        const float* W = sel == 0 ? W0 : (sel == 1 ? W1 : W2);
        short* T = sel == 0 ? T0 : (sel == 1 ? T1 : T2);
        float s = sel == 0 ? qscale : 1.0f;
        int n = idx >> 7, k = idx & 127;
        T[idx] = f2bf(W[k * HD_ + n] * s);
        return;
    }
    int j = gi - 196608;
    if (j < HD_) bqs[j] = bq[j] * qscale;
}

// ---- Stage 1: K/V projection only  (q is projected inside attn) ----
// grid.x: [0,128) k | [128,256) vT ; grid.y = head pair. 128-row M-tiles.
// A-fragments packed in-register from fp32 key (read once, coalesced).
__global__ __launch_bounds__(256, 2) void kvproj_kernel(
    const float* __restrict__ key_,
    const short* __restrict__ wkt, const short* __restrict__ wvt,
    const float* __restrict__ bk, const float* __restrict__ bv,
    short* __restrict__ ks, short* __restrict__ vt)
{
    __shared__ __align__(16) short csh[9216];   // k: [m][n] s72; v: [n][m] s136

    int bx = blockIdx.x;
    const short* Wt; const float* bias; short* out; int transposed;
    if (bx < 128) { Wt = wkt; bias = bk; out = ks; transposed = 0; }
    else { bx -= 128; Wt = wvt; bias = bv; out = vt; transposed = 1; }

    const int tid  = threadIdx.x;
    const int w    = tid >> 6, lane = tid & 63;
    const int l15  = lane & 15, quad = lane >> 4;
    const int mbase = bx * 128;

    // A fragments direct from fp32 key (wave w owns rows [w*32,w*32+32))
    short8 afr[2][4];
    #pragma unroll
    for (int mt = 0; mt < 2; ++mt) {
        const float* xrow = key_ + (size_t)(mbase + w * 32 + mt * 16 + l15) * CQ_;
        #pragma unroll
        for (int kt = 0; kt < 4; ++kt)
            afr[mt][kt] = pack8(*(const float4*)(xrow + kt * 32 + quad * 8),
                                *(const float4*)(xrow + kt * 32 + quad * 8 + 4));
    }

    const int b  = mbase >> 10;
    const int r0 = mbase & 1023;

    #pragma unroll
    for (int hh = 0; hh < 2; ++hh) {
        const int h = blockIdx.y * 2 + hh;
        short8 bfr[4][4];
        #pragma unroll
        for (int nt = 0; nt < 4; ++nt) {
            const short8* wrow = (const short8*)(Wt + (size_t)(h * 64 + nt * 16 + l15) * CQ_);
            #pragma unroll
            for (int kt = 0; kt < 4; ++kt) bfr[nt][kt] = wrow[kt * 4 + quad];
        }
        floatx4 acc[2][4];
        #pragma unroll
        for (int mt = 0; mt < 2; ++mt)
            #pragma unroll
            for (int nt = 0; nt < 4; ++nt) {
                floatx4 a = {0.f, 0.f, 0.f, 0.f};
                #pragma unroll
                for (int kt = 0; kt < 4; ++kt)
                    a = __builtin_amdgcn_mfma_f32_16x16x32_bf16(afr[mt][kt], bfr[nt][kt], a, 0, 0, 0);
                acc[mt][nt] = a;
            }
        __syncthreads();   // previous head's csh reads done
        #pragma unroll
        for (int mt = 0; mt < 2; ++mt)
            #pragma unroll
            for (int nt = 0; nt < 4; ++nt) {
                const float bvv = bias[h * 64 + nt * 16 + l15];
                #pragma unroll
                for (int i = 0; i < 4; ++i) {
                    const short s = f2bf(acc[mt][nt][i] + bvv);
                    const int m = w * 32 + mt * 16 + quad * 4 + i;
                    const int n = nt * 16 + l15;
                    if (!transposed) csh[m * 72 + n]  = s;
                    else             csh[n * 136 + m] = s;
                }
            }
        __syncthreads();

        const size_t bh = (size_t)(b * H_ + h);
        if (!transposed) {
            short* dst = out + (bh * NK_ + r0) * D_;     // contiguous 8192-elem region
            #pragma unroll
            for (int it = 0; it < 4; ++it) {
                const int idx = it * 256 + tid;          // 0..1023
                const int row = idx >> 3, c8 = (idx & 7) * 8;
                *(short8*)(dst + idx * 8) = *(const short8*)&csh[row * 72 + c8];
            }
        } else {
            short* dst = out + bh * D_ * NK_ + r0;       // 64 rows x 128 cols, stride NK
            #pragma unroll
            for (int it = 0; it < 4; ++it) {
                const int idx = it * 256 + tid;
                const int row = idx >> 4, c8 = (idx & 15) * 8;
                *(short8*)(dst + (size_t)row * NK_ + c8) = *(const short8*)&csh[row * 136 + c8];
            }
        }
    }
}

// ---- Stage 2: flash attention with fused Q-projection ----
// grid 512 = (qq bits7-8, bh bits0-6), 256 threads (4 waves, 32 q-rows each).
// Phase A: project this block's Q in-register (swapped MFMA, psh round-trip)
// straight from fp32 query. Main loop: R7-verified double-buffered async K/V
// staging, S^T QK, fixed-max exp2 softmax, swapped-PV O^T epilogue.
__global__ __launch_bounds__(256, 2) void attn_kernel(
    const float* __restrict__ query, const short* __restrict__ ks,
    const short* __restrict__ vt, const float* __restrict__ cmask,
    const short* __restrict__ wqt, const float* __restrict__ bqs,
    float* __restrict__ out)
{
    __shared__ __align__(16) short kbuf[2][64 * 64];
    __shared__ __align__(16) short vbuf[2][64 * 64];
    __shared__ __align__(16) short psh[128 * 64];    // swizzled, wave-private rows

    const int tid = threadIdx.x;
    const int w = tid >> 6, lane = tid & 63;
    const int l15 = lane & 15, quad = lane >> 4;

    const int bx   = blockIdx.x;
    const int bh_i = bx & 127;            // bh%8 tracks dispatch%8 -> XCD locality
    const int qq   = bx >> 7;             // 0..3 (128 q-rows each)
    const int h    = bh_i & 7;
    const int b    = bh_i >> 3;

    const size_t bh = (size_t)bh_i;
    const short* kb_ = ks + bh * NK_ * D_;
    const short* vb  = vt + bh * D_ * NK_;
    const float* mk  = cmask + (size_t)b * NK_;

    // --- Phase A: Q projection (swapped: D[m=d][n=q]) via psh round-trip ---
    short8 qa[2][2];
    {
        short8 waf[4][4];
        #pragma unroll
        for (int dt = 0; dt < 4; ++dt)
            #pragma unroll
            for (int kt = 0; kt < 4; ++kt)
                waf[dt][kt] = *(const short8*)(wqt + (size_t)(h * 64 + dt * 16 + l15) * CQ_ + kt * 32 + quad * 8);
        const int qr0 = qq * 128 + w * 32;
        #pragma unroll
        for (int g = 0; g < 2; ++g) {
            const float* qrow = query + ((size_t)b * NQ_ + qr0 + g * 16 + l15) * CQ_;
            short8 bqf[4];
            #pragma unroll
            for (int kt = 0; kt < 4; ++kt)
                bqf[kt] = pack8(*(const float4*)(qrow + kt * 32 + quad * 8),
                                *(const float4*)(qrow + kt * 32 + quad * 8 + 4));
            const int prow = w * 32 + g * 16 + l15;
            #pragma unroll
            for (int dt = 0; dt < 4; ++dt) {
                float4 bi = *(const float4*)(bqs + h * 64 + dt * 16 + quad * 4);
                floatx4 a = {bi.x, bi.y, bi.z, bi.w};
                #pragma unroll
                for (int kt = 0; kt < 4; ++kt)
                    a = __builtin_amdgcn_mfma_f32_16x16x32_bf16(waf[dt][kt], bqf[kt], a, 0, 0, 0);
                const int c16 = (dt * 2 + (quad >> 1)) ^ (prow & 7);
                *(int2*)&psh[prow * 64 + c16 * 8 + (quad & 1) * 4] = packi2(a);
            }
            qa[g][0] = *(const short8*)&psh[prow * 64 + ((quad    ) ^ (prow & 7)) * 8];
            qa[g][1] = *(const short8*)&psh[prow * 64 + ((4 + quad) ^ (prow & 7)) * 8];
        }
    }

    // staging lane geometry: 8 lanes per row, 8 chunks of 16B per row
    const int srow8 = lane >> 3, sc = lane & 7;

    float l_lane[2] = {0.f, 0.f};
    floatx4 o_acc[2][4];
    #pragma unroll
    for (int g = 0; g < 2; ++g)
        #pragma unroll
        for (int dt = 0; dt < 4; ++dt) o_acc[g][dt] = (floatx4){0.f, 0.f, 0.f, 0.f};

    // prologue: stage tile 0
    #pragma unroll
    for (int j = 0; j < 2; ++j) {
        const int row = w * 16 + j * 8 + srow8;
        const int cs = sc ^ (row & 7);
        async16(kb_ + (size_t)row * D_ + cs * 8, &kbuf[0][(w * 16 + j * 8) * 64]);
        async16(vb + (size_t)row * NK_ + cs * 8, &vbuf[0][(w * 16 + j * 8) * 64]);
    }
    __syncthreads();

    for (int t = 0; t < 16; ++t) {
        const int cur = t & 1;
        if (t < 15) {   // issue next tile's async loads (overlap with compute)
            const int nb = (t + 1) * 64, nxt = cur ^ 1;
            #pragma unroll
            for (int j = 0; j < 2; ++j) {
                const int row = w * 16 + j * 8 + srow8;
                const int cs = sc ^ (row & 7);
                async16(kb_ + (size_t)(nb + row) * D_ + cs * 8, &kbuf[nxt][(w * 16 + j * 8) * 64]);
                async16(vb + (size_t)row * NK_ + nb + cs * 8, &vbuf[nxt][(w * 16 + j * 8) * 64]);
            }
        }
        const short* kb = kbuf[cur];
        const short* vbl = vbuf[cur];
        const int kbase = t * 64;

        // K A-fragments (swizzled reads): A[m=key][k=d]
        short8 ka[4][2];
        #pragma unroll
        for (int nt = 0; nt < 4; ++nt) {
            const int row = nt * 16 + l15;
            ka[nt][0] = *(const short8*)&kb[row * 64 + ((quad    ) ^ (row & 7)) * 8];
            ka[nt][1] = *(const short8*)&kb[row * 64 + ((4 + quad) ^ (row & 7)) * 8];
        }
        // V fragments: lane map serves as A[m=d l15][k=key quad*8+j]
        short8 vf[2][4];
        #pragma unroll
        for (int dt = 0; dt < 4; ++dt) {
            const int row = dt * 16 + l15;
            vf[0][dt] = *(const short8*)&vbl[row * 64 + ((quad    ) ^ (row & 7)) * 8];
            vf[1][dt] = *(const short8*)&vbl[row * 64 + ((4 + quad) ^ (row & 7)) * 8];
        }
        // mask (0/1) for this lane's keys
        float4 m4[4];
        #pragma unroll
        for (int nt = 0; nt < 4; ++nt)
            m4[nt] = *(const float4*)(mk + kbase + nt * 16 + quad * 4);

        #pragma unroll
        for (int g = 0; g < 2; ++g) {
            // S^T = K·Q^T : D[m=key][n=query]
            floatx4 st[4];
            #pragma unroll
            for (int nt = 0; nt < 4; ++nt) {
                floatx4 a = {0.f, 0.f, 0.f, 0.f};
                a = __builtin_amdgcn_mfma_f32_16x16x32_bf16(ka[nt][1], qa[g][1], a, 0, 0, 0);
                a = __builtin_amdgcn_mfma_f32_16x16x32_bf16(ka[nt][0], qa[g][0], a, 0, 0, 0);
                st[nt] = a;
            }
            // p = mask * exp2(s); P -> psh (swizzled int2 writes, wave-private rows)
            const int prow = w * 32 + g * 16 + l15;
            float psum = 0.f;
            #pragma unroll
            for (int nt = 0; nt < 4; ++nt) {
                float p0 = m4[nt].x * __builtin_amdgcn_exp2f(st[nt][0]);
                float p1 = m4[nt].y * __builtin_amdgcn_exp2f(st[nt][1]);
                float p2 = m4[nt].z * __builtin_amdgcn_exp2f(st[nt][2]);
                float p3 = m4[nt].w * __builtin_amdgcn_exp2f(st[nt][3]);
                psum += (p0 + p1) + (p2 + p3);
                int2 pk = make_int2(f2bf_pk(p0, p1), f2bf_pk(p2, p3));
                const int c16 = (2 * nt + (quad >> 1)) ^ (prow & 7);
                *(int2*)&psh[prow * 64 + c16 * 8 + (quad & 1) * 4] = pk;
            }
            l_lane[g] += psum;
            // O^T += V^T·P^T (operand-swapped; same-wave psh write->read)
            #pragma unroll
            for (int kt = 0; kt < 2; ++kt) {
                short8 pa = *(const short8*)&psh[prow * 64 + ((kt * 4 + quad) ^ (prow & 7)) * 8];
                #pragma unroll
                for (int dt = 0; dt < 4; ++dt)
                    o_acc[g][dt] = __builtin_amdgcn_mfma_f32_16x16x32_bf16(vf[kt][dt], pa, o_acc[g][dt], 0, 0, 0);
            }
        }
        __syncthreads();   // next tile staged + all waves done with this buffer
    }

    // epilogue: O^T layout => q=l15, d=dt*16+quad*4+i; float4 stores
    #pragma unroll
    for (int g = 0; g < 2; ++g) {
        float ls = l_lane[g];
        ls += __shfl_xor(ls, 16);
        ls += __shfl_xor(ls, 32);
        const float linv = 1.0f / ls;
        const int qr = qq * 128 + w * 32 + g * 16 + l15;
        float* orow = out + ((size_t)b * NQ_ + qr) * HD_ + h * D_;
        #pragma unroll
        for (int dt = 0; dt < 4; ++dt) {
            float4 v = make_float4(o_acc[g][dt][0] * linv, o_acc[g][dt][1] * linv,
                                   o_acc[g][dt][2] * linv, o_acc[g][dt][3] * linv);
            *(float4*)(orow + dt * 16 + quad * 4) = v;
        }
    }
}

extern "C" void kernel_launch(void* const* d_in, const int* in_sizes, int n_in,
                              void* d_out, int out_size, void* d_ws, size_t ws_size,
                              hipStream_t stream) {
    const float* query = (const float*)d_in[0];
    const float* key   = (const float*)d_in[1];
    const float* cmask = (const float*)d_in[2];
    const float* Wq    = (const float*)d_in[3];
    const float* bq    = (const float*)d_in[4];
    const float* Wk    = (const float*)d_in[5];
    const float* bk    = (const float*)d_in[6];
    const float* Wv    = (const float*)d_in[7];
    const float* bv    = (const float*)d_in[8];
    float* out = (float*)d_out;

    char* ws = (char*)d_ws;
    short* ks  = (short*)(ws);                           // 16 MB (B*H*NK*D bf16)
    short* vt  = (short*)(ws + (size_t)(16u << 20));     // 16 MB (B*H*D*NK bf16)
    char*  w32 = ws + (size_t)(32u << 20);
    short* wqt = (short*)(w32);                          // 128 KB each
    short* wkt = (short*)(w32 + 131072);
    short* wvt = (short*)(w32 + 131072 * 2);
    float* bqs = (float*)(w32 + 131072 * 3);             // 2 KB

    const float qscale = 0.125f * 1.44269504f;    // 1/sqrt(64) * log2(e)
    prep_kernel<<<dim3(771), dim3(256), 0, stream>>>(
        Wq, Wk, Wv, wqt, wkt, wvt, bq, bqs, qscale);

    kvproj_kernel<<<dim3(256, 4), dim3(256), 0, stream>>>(
        key, wkt, wvt, bk, bv, ks, vt);

    attn_kernel<<<dim3(512), dim3(256), 0, stream>>>(
        query, ks, vt, cmask, wqt, bqs, out);
}

// Round 11
// 146.702 us; speedup vs baseline: 1.3851x; 1.0065x over previous
//
#include <hip/hip_runtime.h>
#include <hip/hip_bf16.h>

#define B_  16
#define NQ_ 512
#define NK_ 1024
#define CQ_ 128
#define H_  8
#define D_  64
#define HD_ 512   // H*D

typedef __attribute__((ext_vector_type(8))) short short8;
typedef __attribute__((ext_vector_type(4))) float floatx4;

__device__ __forceinline__ short f2bf(float f) {
    union { float f; unsigned u; } x; x.f = f;
    unsigned r = (x.u + 0x7fffu + ((x.u >> 16) & 1u)) >> 16;  // RNE
    return (short)r;
}
__device__ __forceinline__ int f2bf_pk(float a, float b) {   // packed RNE (v_cvt_pk_bf16_f32)
    __hip_bfloat162 h = __float22bfloat162_rn(make_float2(a, b));
    int r; __builtin_memcpy(&r, &h, 4); return r;
}
__device__ __forceinline__ short8 pack8(float4 a, float4 b) {
    union { int4 i; short8 s; } u;
    u.i = make_int4(f2bf_pk(a.x, a.y), f2bf_pk(a.z, a.w),
                    f2bf_pk(b.x, b.y), f2bf_pk(b.z, b.w));
    return u.s;
}
__device__ __forceinline__ int2 packi2(floatx4 a) {
    return make_int2(f2bf_pk(a[0], a[1]), f2bf_pk(a[2], a[3]));
}
// async global->LDS, 16B per lane; LDS dest = uniform base + lane*16
__device__ __forceinline__ void async16(const short* g, short* l) {
    __builtin_amdgcn_global_load_lds(
        (const __attribute__((address_space(1))) void*)g,
        (__attribute__((address_space(3))) void*)l, 16, 0, 0);
}

// ---- Stage 0 (prep): LDS-tiled transpose W[128][512] fp32 -> Wt[512][128]
// bf16 (x3, coalesced both sides); qscale folded into wqt and bqs.
// blocks 0..47: mat = blk/16, 32 n-cols each. block 48: bqs.
__global__ __launch_bounds__(256) void prep_kernel(
    const float* __restrict__ W0, const float* __restrict__ W1,
    const float* __restrict__ W2, short* __restrict__ T0,
    short* __restrict__ T1, short* __restrict__ T2,
    const float* __restrict__ bq, float* __restrict__ bqs, float qscale)
{
    const int blk = blockIdx.x, t = threadIdx.x;
    if (blk == 48) {
        bqs[t]       = bq[t] * qscale;
        bqs[t + 256] = bq[t + 256] * qscale;
        return;
    }
    __shared__ short tsh[32 * 132];    // [n][k], pad 132
    const int mat = blk >> 4, nb = blk & 15;          // n0 = nb*32
    const float* W = mat == 0 ? W0 : (mat == 1 ? W1 : W2);
    short* T = mat == 0 ? T0 : (mat == 1 ? T1 : T2);
    const float s = mat == 0 ? qscale : 1.0f;

    // read coalesced: 128 k-rows x 32 n-cols (float4), scatter bf16 to tsh[n][k]
    #pragma unroll
    for (int i = 0; i < 4; ++i) {
        const int idx = i * 256 + t;                  // 0..1023
        const int k = idx >> 3, c = (idx & 7) * 4;
        float4 v = *(const float4*)(W + (size_t)k * HD_ + nb * 32 + c);
        tsh[(c + 0) * 132 + k] = f2bf(v.x * s);
        tsh[(c + 1) * 132 + k] = f2bf(v.y * s);
        tsh[(c + 2) * 132 + k] = f2bf(v.z * s);
        tsh[(c + 3) * 132 + k] = f2bf(v.w * s);
    }
    __syncthreads();
    // write coalesced: 32 n-rows x 128 k (short8 per lane, contiguous)
    #pragma unroll
    for (int j = 0; j < 2; ++j) {
        const int idx = j * 256 + t;                  // 0..511
        const int n = idx >> 4, seg = (idx & 15) * 8;
        *(short8*)(T + (size_t)(nb * 32 + n) * CQ_ + seg) =
            *(const short8*)&tsh[n * 132 + seg];
    }
}

// ---- Stage 1: K/V projection only, 4 heads per block ----
// grid.x: [0,128) k | [128,256) vT ; grid.y: head quad (heads 4y..4y+3).
__global__ __launch_bounds__(256, 2) void kvproj_kernel(
    const float* __restrict__ key_,
    const short* __restrict__ wkt, const short* __restrict__ wvt,
    const float* __restrict__ bk, const float* __restrict__ bv,
    short* __restrict__ ks, short* __restrict__ vt)
{
    __shared__ __align__(16) short csh[9216];   // k: [m][n] s72; v: [n][m] s136

    int bx = blockIdx.x;
    const short* Wt; const float* bias; short* out; int transposed;
    if (bx < 128) { Wt = wkt; bias = bk; out = ks; transposed = 0; }
    else { bx -= 128; Wt = wvt; bias = bv; out = vt; transposed = 1; }

    const int tid  = threadIdx.x;
    const int w    = tid >> 6, lane = tid & 63;
    const int l15  = lane & 15, quad = lane >> 4;
    const int mbase = bx * 128;

    // A fragments direct from fp32 key (wave w owns rows [w*32,w*32+32))
    short8 afr[2][4];
    #pragma unroll
    for (int mt = 0; mt < 2; ++mt) {
        const float* xrow = key_ + (size_t)(mbase + w * 32 + mt * 16 + l15) * CQ_;
        #pragma unroll
        for (int kt = 0; kt < 4; ++kt)
            afr[mt][kt] = pack8(*(const float4*)(xrow + kt * 32 + quad * 8),
                                *(const float4*)(xrow + kt * 32 + quad * 8 + 4));
    }

    const int b  = mbase >> 10;
    const int r0 = mbase & 1023;

    #pragma unroll
    for (int hh = 0; hh < 4; ++hh) {
        const int h = blockIdx.y * 4 + hh;
        short8 bfr[4][4];
        #pragma unroll
        for (int nt = 0; nt < 4; ++nt) {
            const short8* wrow = (const short8*)(Wt + (size_t)(h * 64 + nt * 16 + l15) * CQ_);
            #pragma unroll
            for (int kt = 0; kt < 4; ++kt) bfr[nt][kt] = wrow[kt * 4 + quad];
        }
        floatx4 acc[2][4];
        #pragma unroll
        for (int mt = 0; mt < 2; ++mt)
            #pragma unroll
            for (int nt = 0; nt < 4; ++nt) {
                floatx4 a = {0.f, 0.f, 0.f, 0.f};
                #pragma unroll
                for (int kt = 0; kt < 4; ++kt)
                    a = __builtin_amdgcn_mfma_f32_16x16x32_bf16(afr[mt][kt], bfr[nt][kt], a, 0, 0, 0);
                acc[mt][nt] = a;
            }
        __syncthreads();   // previous head's csh reads done
        #pragma unroll
        for (int mt = 0; mt < 2; ++mt)
            #pragma unroll
            for (int nt = 0; nt < 4; ++nt) {
                const float bvv = bias[h * 64 + nt * 16 + l15];
                #pragma unroll
                for (int i = 0; i < 4; ++i) {
                    const short s = f2bf(acc[mt][nt][i] + bvv);
                    const int m = w * 32 + mt * 16 + quad * 4 + i;
                    const int n = nt * 16 + l15;
                    if (!transposed) csh[m * 72 + n]  = s;
                    else             csh[n * 136 + m] = s;
                }
            }
        __syncthreads();

        const size_t bh = (size_t)(b * H_ + h);
        if (!transposed) {
            short* dst = out + (bh * NK_ + r0) * D_;     // contiguous 8192-elem region
            #pragma unroll
            for (int it = 0; it < 4; ++it) {
                const int idx = it * 256 + tid;          // 0..1023
                const int row = idx >> 3, c8 = (idx & 7) * 8;
                *(short8*)(dst + idx * 8) = *(const short8*)&csh[row * 72 + c8];
            }
        } else {
            short* dst = out + bh * D_ * NK_ + r0;       // 64 rows x 128 cols, stride NK
            #pragma unroll
            for (int it = 0; it < 4; ++it) {
                const int idx = it * 256 + tid;
                const int row = idx >> 4, c8 = (idx & 15) * 8;
                *(short8*)(dst + (size_t)row * NK_ + c8) = *(const short8*)&csh[row * 136 + c8];
            }
        }
    }
}

// ---- Stage 2: flash attention with fused Q-projection ----
// grid 512 = (qq bits7-8, bh bits0-6), 256 threads (4 waves, 32 q-rows each).
// Double-buffered 128-key phases (2 chunks per barrier -> 8 barriers instead
// of 16; halves the vmcnt(0)+s_barrier drain overhead). Phase A Q-projection,
// S^T QK, fixed-max exp2 softmax, swapped-PV O^T epilogue as verified in R10.
__global__ __launch_bounds__(256, 2) void attn_kernel(
    const float* __restrict__ query, const short* __restrict__ ks,
    const short* __restrict__ vt, const float* __restrict__ cmask,
    const short* __restrict__ wqt, const float* __restrict__ bqs,
    float* __restrict__ out)
{
    __shared__ __align__(16) short kbuf[2][2][64 * 64];   // [phase][sub][key][d]
    __shared__ __align__(16) short vbuf[2][2][64 * 64];   // [phase][sub][d][key]
    __shared__ __align__(16) short psh[128 * 64];         // swizzled, wave-private rows

    const int tid = threadIdx.x;
    const int w = tid >> 6, lane = tid & 63;
    const int l15 = lane & 15, quad = lane >> 4;

    const int bx   = blockIdx.x;
    const int bh_i = bx & 127;            // bh%8 tracks dispatch%8 -> XCD locality
    const int qq   = bx >> 7;             // 0..3 (128 q-rows each)
    const int h    = bh_i & 7;
    const int b    = bh_i >> 3;

    const size_t bh = (size_t)bh_i;
    const short* kb_ = ks + bh * NK_ * D_;
    const short* vb  = vt + bh * D_ * NK_;
    const float* mk  = cmask + (size_t)b * NK_;

    // --- Phase A: Q projection (swapped: D[m=d][n=q]) via psh round-trip ---
    short8 qa[2][2];
    {
        short8 waf[4][4];
        #pragma unroll
        for (int dt = 0; dt < 4; ++dt)
            #pragma unroll
            for (int kt = 0; kt < 4; ++kt)
                waf[dt][kt] = *(const short8*)(wqt + (size_t)(h * 64 + dt * 16 + l15) * CQ_ + kt * 32 + quad * 8);
        const int qr0 = qq * 128 + w * 32;
        #pragma unroll
        for (int g = 0; g < 2; ++g) {
            const float* qrow = query + ((size_t)b * NQ_ + qr0 + g * 16 + l15) * CQ_;
            short8 bqf[4];
            #pragma unroll
            for (int kt = 0; kt < 4; ++kt)
                bqf[kt] = pack8(*(const float4*)(qrow + kt * 32 + quad * 8),
                                *(const float4*)(qrow + kt * 32 + quad * 8 + 4));
            const int prow = w * 32 + g * 16 + l15;
            #pragma unroll
            for (int dt = 0; dt < 4; ++dt) {
                float4 bi = *(const float4*)(bqs + h * 64 + dt * 16 + quad * 4);
                floatx4 a = {bi.x, bi.y, bi.z, bi.w};
                #pragma unroll
                for (int kt = 0; kt < 4; ++kt)
                    a = __builtin_amdgcn_mfma_f32_16x16x32_bf16(waf[dt][kt], bqf[kt], a, 0, 0, 0);
                const int c16 = (dt * 2 + (quad >> 1)) ^ (prow & 7);
                *(int2*)&psh[prow * 64 + c16 * 8 + (quad & 1) * 4] = packi2(a);
            }
            qa[g][0] = *(const short8*)&psh[prow * 64 + ((quad    ) ^ (prow & 7)) * 8];
            qa[g][1] = *(const short8*)&psh[prow * 64 + ((4 + quad) ^ (prow & 7)) * 8];
        }
    }

    // staging lane geometry: 8 lanes per row, 8 chunks of 16B per row
    const int srow8 = lane >> 3, sc = lane & 7;
    auto stage = [&](int kb0, short (*kdst)[4096], short (*vdst)[4096]) {
        #pragma unroll
        for (int sub = 0; sub < 2; ++sub)
            #pragma unroll
            for (int j = 0; j < 2; ++j) {
                const int row = w * 16 + j * 8 + srow8;
                const int cs = sc ^ (row & 7);
                async16(kb_ + (size_t)(kb0 + sub * 64 + row) * D_ + cs * 8,
                        &kdst[sub][(w * 16 + j * 8) * 64]);
                async16(vb + (size_t)row * NK_ + kb0 + sub * 64 + cs * 8,
                        &vdst[sub][(w * 16 + j * 8) * 64]);
            }
    };

    float l_lane[2] = {0.f, 0.f};
    floatx4 o_acc[2][4];
    #pragma unroll
    for (int g = 0; g < 2; ++g)
        #pragma unroll
        for (int dt = 0; dt < 4; ++dt) o_acc[g][dt] = (floatx4){0.f, 0.f, 0.f, 0.f};

    stage(0, kbuf[0], vbuf[0]);
    __syncthreads();

    for (int ph = 0; ph < 8; ++ph) {
        const int cur = ph & 1;
        if (ph < 7) stage((ph + 1) * 128, kbuf[cur ^ 1], vbuf[cur ^ 1]);

        #pragma unroll
        for (int sub = 0; sub < 2; ++sub) {
            const short* kb  = kbuf[cur][sub];
            const short* vbl = vbuf[cur][sub];
            const int kbase = ph * 128 + sub * 64;

            // K A-fragments (swizzled): A[m=key][k=d]
            short8 ka[4][2];
            #pragma unroll
            for (int nt = 0; nt < 4; ++nt) {
                const int row = nt * 16 + l15;
                ka[nt][0] = *(const short8*)&kb[row * 64 + ((quad    ) ^ (row & 7)) * 8];
                ka[nt][1] = *(const short8*)&kb[row * 64 + ((4 + quad) ^ (row & 7)) * 8];
            }
            // V fragments: lane map serves as A[m=d l15][k=key quad*8+j]
            short8 vf[2][4];
            #pragma unroll
            for (int dt = 0; dt < 4; ++dt) {
                const int row = dt * 16 + l15;
                vf[0][dt] = *(const short8*)&vbl[row * 64 + ((quad    ) ^ (row & 7)) * 8];
                vf[1][dt] = *(const short8*)&vbl[row * 64 + ((4 + quad) ^ (row & 7)) * 8];
            }
            // mask (0/1) for this lane's keys
            float4 m4[4];
            #pragma unroll
            for (int nt = 0; nt < 4; ++nt)
                m4[nt] = *(const float4*)(mk + kbase + nt * 16 + quad * 4);

            #pragma unroll
            for (int g = 0; g < 2; ++g) {
                // S^T = K·Q^T : D[m=key][n=query]
                floatx4 st[4];
                #pragma unroll
                for (int nt = 0; nt < 4; ++nt) {
                    floatx4 a = {0.f, 0.f, 0.f, 0.f};
                    a = __builtin_amdgcn_mfma_f32_16x16x32_bf16(ka[nt][1], qa[g][1], a, 0, 0, 0);
                    a = __builtin_amdgcn_mfma_f32_16x16x32_bf16(ka[nt][0], qa[g][0], a, 0, 0, 0);
                    st[nt] = a;
                }
                // p = mask * exp2(s); P -> psh (swizzled, wave-private rows)
                const int prow = w * 32 + g * 16 + l15;
                float psum = 0.f;
                #pragma unroll
                for (int nt = 0; nt < 4; ++nt) {
                    float p0 = m4[nt].x * __builtin_amdgcn_exp2f(st[nt][0]);
                    float p1 = m4[nt].y * __builtin_amdgcn_exp2f(st[nt][1]);
                    float p2 = m4[nt].z * __builtin_amdgcn_exp2f(st[nt][2]);
                    float p3 = m4[nt].w * __builtin_amdgcn_exp2f(st[nt][3]);
                    psum += (p0 + p1) + (p2 + p3);
                    int2 pk = make_int2(f2bf_pk(p0, p1), f2bf_pk(p2, p3));
                    const int c16 = (2 * nt + (quad >> 1)) ^ (prow & 7);
                    *(int2*)&psh[prow * 64 + c16 * 8 + (quad & 1) * 4] = pk;
                }
                l_lane[g] += psum;
                // O^T += V^T·P^T (operand-swapped; same-wave psh write->read)
                #pragma unroll
                for (int kt = 0; kt < 2; ++kt) {
                    short8 pa = *(const short8*)&psh[prow * 64 + ((kt * 4 + quad) ^ (prow & 7)) * 8];
                    #pragma unroll
                    for (int dt = 0; dt < 4; ++dt)
                        o_acc[g][dt] = __builtin_amdgcn_mfma_f32_16x16x32_bf16(vf[kt][dt], pa, o_acc[g][dt], 0, 0, 0);
                }
            }
        }
        __syncthreads();   // next phase staged + all waves done with this buffer
    }

    // epilogue: O^T layout => q=l15, d=dt*16+quad*4+i; float4 stores
    #pragma unroll
    for (int g = 0; g < 2; ++g) {
        float ls = l_lane[g];
        ls += __shfl_xor(ls, 16);
        ls += __shfl_xor(ls, 32);
        const float linv = 1.0f / ls;
        const int qr = qq * 128 + w * 32 + g * 16 + l15;
        float* orow = out + ((size_t)b * NQ_ + qr) * HD_ + h * D_;
        #pragma unroll
        for (int dt = 0; dt < 4; ++dt) {
            float4 v = make_float4(o_acc[g][dt][0] * linv, o_acc[g][dt][1] * linv,
                                   o_acc[g][dt][2] * linv, o_acc[g][dt][3] * linv);
            *(float4*)(orow + dt * 16 + quad * 4) = v;
        }
    }
}

extern "C" void kernel_launch(void* const* d_in, const int* in_sizes, int n_in,
                              void* d_out, int out_size, void* d_ws, size_t ws_size,
                              hipStream_t stream) {
    const float* query = (const float*)d_in[0];
    const float* key   = (const float*)d_in[1];
    const float* cmask = (const float*)d_in[2];
    const float* Wq    = (const float*)d_in[3];
    const float* bq    = (const float*)d_in[4];
    const float* Wk    = (const float*)d_in[5];
    const float* bk    = (const float*)d_in[6];
    const float* Wv    = (const float*)d_in[7];
    const float* bv    = (const float*)d_in[8];
    float* out = (float*)d_out;

    char* ws = (char*)d_ws;
    short* ks  = (short*)(ws);                           // 16 MB (B*H*NK*D bf16)
    short* vt  = (short*)(ws + (size_t)(16u << 20));     // 16 MB (B*H*D*NK bf16)
    char*  w32 = ws + (size_t)(32u << 20);
    short* wqt = (short*)(w32);                          // 128 KB each
    short* wkt = (short*)(w32 + 131072);
    short* wvt = (short*)(w32 + 131072 * 2);
    float* bqs = (float*)(w32 + 131072 * 3);             // 2 KB

    const float qscale = 0.125f * 1.44269504f;    // 1/sqrt(64) * log2(e)
    prep_kernel<<<dim3(49), dim3(256), 0, stream>>>(
        Wq, Wk, Wv, wqt, wkt, wvt, bq, bqs, qscale);

    kvproj_kernel<<<dim3(256, 2), dim3(256), 0, stream>>>(
        key, wkt, wvt, bk, bv, ks, vt);

    attn_kernel<<<dim3(512), dim3(256), 0, stream>>>(
        query, ks, vt, cmask, wqt, bqs, out);
}

// Round 12
// 135.568 us; speedup vs baseline: 1.4988x; 1.0821x over previous
//
#include <hip/hip_runtime.h>
#include <hip/hip_bf16.h>

#define B_  16
#define NQ_ 512
#define NK_ 1024
#define CQ_ 128
#define H_  8
#define D_  64
#define HD_ 512   // H*D

typedef __attribute__((ext_vector_type(8))) short short8;
typedef __attribute__((ext_vector_type(4))) float floatx4;

__device__ __forceinline__ short f2bf(float f) {
    union { float f; unsigned u; } x; x.f = f;
    unsigned r = (x.u + 0x7fffu + ((x.u >> 16) & 1u)) >> 16;  // RNE
    return (short)r;
}
__device__ __forceinline__ int f2bf_pk(float a, float b) {   // packed RNE (v_cvt_pk_bf16_f32)
    __hip_bfloat162 h = __float22bfloat162_rn(make_float2(a, b));
    int r; __builtin_memcpy(&r, &h, 4); return r;
}
__device__ __forceinline__ short8 pack8(float4 a, float4 b) {
    union { int4 i; short8 s; } u;
    u.i = make_int4(f2bf_pk(a.x, a.y), f2bf_pk(a.z, a.w),
                    f2bf_pk(b.x, b.y), f2bf_pk(b.z, b.w));
    return u.s;
}
__device__ __forceinline__ int2 packi2(floatx4 a) {
    return make_int2(f2bf_pk(a[0], a[1]), f2bf_pk(a[2], a[3]));
}
// async global->LDS, 16B per lane; LDS dest = uniform base + lane*16
__device__ __forceinline__ void async16(const short* g, short* l) {
    __builtin_amdgcn_global_load_lds(
        (const __attribute__((address_space(1))) void*)g,
        (__attribute__((address_space(3))) void*)l, 16, 0, 0);
}

// ---- Stage 0 (prep): W transposes + bqs + per-batch mask compaction ----
// blocks 0..47: LDS-tiled transpose W[128][512] -> Wt[512][128] bf16.
// block 48: bqs = bq*qscale.
// blocks 49..64: batch b=blk-49 mask compaction: idx[b][*] = unmasked key
// positions (order-preserving), cm2[b][*] = 1.0 (0.0 for pad), npad[b] =
// count rounded up to 128. Pad slots alias key row 0 (finite values, exact-0
// contribution via mask) so dropped keys change nothing.
__global__ __launch_bounds__(256) void prep_kernel(
    const float* __restrict__ W0, const float* __restrict__ W1,
    const float* __restrict__ W2, short* __restrict__ T0,
    short* __restrict__ T1, short* __restrict__ T2,
    const float* __restrict__ bq, float* __restrict__ bqs, float qscale,
    const float* __restrict__ cmask, int* __restrict__ idx,
    float* __restrict__ cm2, int* __restrict__ npad)
{
    const int blk = blockIdx.x, t = threadIdx.x;
    if (blk == 48) {
        bqs[t]       = bq[t] * qscale;
        bqs[t + 256] = bq[t + 256] * qscale;
        return;
    }
    if (blk >= 49) {   // ---- mask compaction for batch b ----
        __shared__ int wsum[4];
        const int b = blk - 49;
        const int w = t >> 6, lane = t & 63;
        float4 m4 = *(const float4*)(cmask + b * NK_ + t * 4);
        const int m0 = m4.x > 0.5f, m1 = m4.y > 0.5f, m2 = m4.z > 0.5f, m3 = m4.w > 0.5f;
        const int s = m0 + m1 + m2 + m3;
        int v = s;
        #pragma unroll
        for (int off = 1; off < 64; off <<= 1) {
            int u = __shfl_up(v, off);
            if (lane >= off) v += u;
        }
        if (lane == 63) wsum[w] = v;
        __syncthreads();
        int pre = 0;
        #pragma unroll
        for (int i = 0; i < 4; ++i) if (i < w) pre += wsum[i];
        int pos = pre + v - s;                 // exclusive prefix for this thread
        const int base = b * NK_;
        if (m0) { idx[base + pos] = t * 4 + 0; cm2[base + pos] = 1.0f; ++pos; }
        if (m1) { idx[base + pos] = t * 4 + 1; cm2[base + pos] = 1.0f; ++pos; }
        if (m2) { idx[base + pos] = t * 4 + 2; cm2[base + pos] = 1.0f; ++pos; }
        if (m3) { idx[base + pos] = t * 4 + 3; cm2[base + pos] = 1.0f; ++pos; }
        const int total = wsum[0] + wsum[1] + wsum[2] + wsum[3];
        for (int j = total + t; j < NK_; j += 256) {   // pad slots
            idx[base + j] = 0; cm2[base + j] = 0.0f;
        }
        if (t == 0) npad[b] = (total + 127) & ~127;
        return;
    }
    // ---- W transpose ----
    __shared__ short tsh[32 * 132];    // [n][k], pad 132
    const int mat = blk >> 4, nb = blk & 15;          // n0 = nb*32
    const float* W = mat == 0 ? W0 : (mat == 1 ? W1 : W2);
    short* T = mat == 0 ? T0 : (mat == 1 ? T1 : T2);
    const float s = mat == 0 ? qscale : 1.0f;
    #pragma unroll
    for (int i = 0; i < 4; ++i) {
        const int i2 = i * 256 + t;                   // 0..1023
        const int k = i2 >> 3, c = (i2 & 7) * 4;
        float4 v = *(const float4*)(W + (size_t)k * HD_ + nb * 32 + c);
        tsh[(c + 0) * 132 + k] = f2bf(v.x * s);
        tsh[(c + 1) * 132 + k] = f2bf(v.y * s);
        tsh[(c + 2) * 132 + k] = f2bf(v.z * s);
        tsh[(c + 3) * 132 + k] = f2bf(v.w * s);
    }
    __syncthreads();
    #pragma unroll
    for (int j = 0; j < 2; ++j) {
        const int i2 = j * 256 + t;                   // 0..511
        const int n = i2 >> 4, seg = (i2 & 15) * 8;
        *(short8*)(T + (size_t)(nb * 32 + n) * CQ_ + seg) =
            *(const short8*)&tsh[n * 132 + seg];
    }
}

// ---- Stage 1: K/V projection over COMPACTED keys, 4 heads per block ----
// grid.x: [0,128) k | [128,256) vT ; grid.y: head quad. Blocks whose 128-row
// tile lies beyond npad[b] exit immediately (block-uniform, pre-barrier).
__global__ __launch_bounds__(256, 2) void kvproj_kernel(
    const float* __restrict__ key_,
    const short* __restrict__ wkt, const short* __restrict__ wvt,
    const float* __restrict__ bk, const float* __restrict__ bv,
    short* __restrict__ ks, short* __restrict__ vt,
    const int* __restrict__ idx, const int* __restrict__ npad)
{
    __shared__ __align__(16) short csh[9216];   // k: [m][n] s72; v: [n][m] s136

    int bx = blockIdx.x;
    const short* Wt; const float* bias; short* out; int transposed;
    if (bx < 128) { Wt = wkt; bias = bk; out = ks; transposed = 0; }
    else { bx -= 128; Wt = wvt; bias = bv; out = vt; transposed = 1; }

    const int mbase = bx * 128;
    const int b  = mbase >> 10;
    const int r0 = mbase & 1023;
    if (r0 >= npad[b]) return;                  // compacted tail: nothing to do

    const int tid  = threadIdx.x;
    const int w    = tid >> 6, lane = tid & 63;
    const int l15  = lane & 15, quad = lane >> 4;
    const int* ib = idx + b * NK_;

    // A fragments gathered from fp32 key rows (rows 512B contiguous)
    short8 afr[2][4];
    #pragma unroll
    for (int mt = 0; mt < 2; ++mt) {
        const int krow = ib[r0 + w * 32 + mt * 16 + l15];
        const float* xrow = key_ + (size_t)(b * NK_ + krow) * CQ_;
        #pragma unroll
        for (int kt = 0; kt < 4; ++kt)
            afr[mt][kt] = pack8(*(const float4*)(xrow + kt * 32 + quad * 8),
                                *(const float4*)(xrow + kt * 32 + quad * 8 + 4));
    }

    #pragma unroll
    for (int hh = 0; hh < 4; ++hh) {
        const int h = blockIdx.y * 4 + hh;
        short8 bfr[4][4];
        #pragma unroll
        for (int nt = 0; nt < 4; ++nt) {
            const short8* wrow = (const short8*)(Wt + (size_t)(h * 64 + nt * 16 + l15) * CQ_);
            #pragma unroll
            for (int kt = 0; kt < 4; ++kt) bfr[nt][kt] = wrow[kt * 4 + quad];
        }
        floatx4 acc[2][4];
        #pragma unroll
        for (int mt = 0; mt < 2; ++mt)
            #pragma unroll
            for (int nt = 0; nt < 4; ++nt) {
                floatx4 a = {0.f, 0.f, 0.f, 0.f};
                #pragma unroll
                for (int kt = 0; kt < 4; ++kt)
                    a = __builtin_amdgcn_mfma_f32_16x16x32_bf16(afr[mt][kt], bfr[nt][kt], a, 0, 0, 0);
                acc[mt][nt] = a;
            }
        __syncthreads();   // previous head's csh reads done
        #pragma unroll
        for (int mt = 0; mt < 2; ++mt)
            #pragma unroll
            for (int nt = 0; nt < 4; ++nt) {
                const float bvv = bias[h * 64 + nt * 16 + l15];
                #pragma unroll
                for (int i = 0; i < 4; ++i) {
                    const short s = f2bf(acc[mt][nt][i] + bvv);
                    const int m = w * 32 + mt * 16 + quad * 4 + i;
                    const int n = nt * 16 + l15;
                    if (!transposed) csh[m * 72 + n]  = s;
                    else             csh[n * 136 + m] = s;
                }
            }
        __syncthreads();

        const size_t bh = (size_t)(b * H_ + h);
        if (!transposed) {
            short* dst = out + (bh * NK_ + r0) * D_;     // contiguous 8192-elem region
            #pragma unroll
            for (int it = 0; it < 4; ++it) {
                const int i2 = it * 256 + tid;           // 0..1023
                const int row = i2 >> 3, c8 = (i2 & 7) * 8;
                *(short8*)(dst + i2 * 8) = *(const short8*)&csh[row * 72 + c8];
            }
        } else {
            short* dst = out + bh * D_ * NK_ + r0;       // 64 rows x 128 cols, stride NK
            #pragma unroll
            for (int it = 0; it < 4; ++it) {
                const int i2 = it * 256 + tid;
                const int row = i2 >> 4, c8 = (i2 & 15) * 8;
                *(short8*)(dst + (size_t)row * NK_ + c8) = *(const short8*)&csh[row * 136 + c8];
            }
        }
    }
}

// ---- Stage 2: flash attention over compacted keys, fused Q-projection ----
// grid 512 = (qq bits7-8, bh bits0-6), 256 threads (4 waves, 32 q-rows each).
// Dynamic chunk count nc = npad[b]/64 (~8 instead of 16). Structure otherwise
// identical to the R10-verified kernel.
__global__ __launch_bounds__(256, 2) void attn_kernel(
    const float* __restrict__ query, const short* __restrict__ ks,
    const short* __restrict__ vt, const float* __restrict__ cm2,
    const short* __restrict__ wqt, const float* __restrict__ bqs,
    const int* __restrict__ npad, float* __restrict__ out)
{
    __shared__ __align__(16) short kbuf[2][64 * 64];
    __shared__ __align__(16) short vbuf[2][64 * 64];
    __shared__ __align__(16) short psh[128 * 64];    // swizzled, wave-private rows

    const int tid = threadIdx.x;
    const int w = tid >> 6, lane = tid & 63;
    const int l15 = lane & 15, quad = lane >> 4;

    const int bx   = blockIdx.x;
    const int bh_i = bx & 127;            // bh%8 tracks dispatch%8 -> XCD locality
    const int qq   = bx >> 7;             // 0..3 (128 q-rows each)
    const int h    = bh_i & 7;
    const int b    = bh_i >> 3;

    const size_t bh = (size_t)bh_i;
    const short* kb_ = ks + bh * NK_ * D_;
    const short* vb  = vt + bh * D_ * NK_;
    const float* mk  = cm2 + (size_t)b * NK_;
    const int nc = npad[b] >> 6;          // compacted chunk count

    // --- Phase A: Q projection (swapped: D[m=d][n=q]) via psh round-trip ---
    short8 qa[2][2];
    {
        short8 waf[4][4];
        #pragma unroll
        for (int dt = 0; dt < 4; ++dt)
            #pragma unroll
            for (int kt = 0; kt < 4; ++kt)
                waf[dt][kt] = *(const short8*)(wqt + (size_t)(h * 64 + dt * 16 + l15) * CQ_ + kt * 32 + quad * 8);
        const int qr0 = qq * 128 + w * 32;
        #pragma unroll
        for (int g = 0; g < 2; ++g) {
            const float* qrow = query + ((size_t)b * NQ_ + qr0 + g * 16 + l15) * CQ_;
            short8 bqf[4];
            #pragma unroll
            for (int kt = 0; kt < 4; ++kt)
                bqf[kt] = pack8(*(const float4*)(qrow + kt * 32 + quad * 8),
                                *(const float4*)(qrow + kt * 32 + quad * 8 + 4));
            const int prow = w * 32 + g * 16 + l15;
            #pragma unroll
            for (int dt = 0; dt < 4; ++dt) {
                float4 bi = *(const float4*)(bqs + h * 64 + dt * 16 + quad * 4);
                floatx4 a = {bi.x, bi.y, bi.z, bi.w};
                #pragma unroll
                for (int kt = 0; kt < 4; ++kt)
                    a = __builtin_amdgcn_mfma_f32_16x16x32_bf16(waf[dt][kt], bqf[kt], a, 0, 0, 0);
                const int c16 = (dt * 2 + (quad >> 1)) ^ (prow & 7);
                *(int2*)&psh[prow * 64 + c16 * 8 + (quad & 1) * 4] = packi2(a);
            }
            qa[g][0] = *(const short8*)&psh[prow * 64 + ((quad    ) ^ (prow & 7)) * 8];
            qa[g][1] = *(const short8*)&psh[prow * 64 + ((4 + quad) ^ (prow & 7)) * 8];
        }
    }

    // staging lane geometry: 8 lanes per row, 8 chunks of 16B per row
    const int srow8 = lane >> 3, sc = lane & 7;
    auto stage = [&](int kb0, short* kdst, short* vdst) {
        #pragma unroll
        for (int j = 0; j < 2; ++j) {
            const int row = w * 16 + j * 8 + srow8;
            const int cs = sc ^ (row & 7);
            async16(kb_ + (size_t)(kb0 + row) * D_ + cs * 8, &kdst[(w * 16 + j * 8) * 64]);
            async16(vb + (size_t)row * NK_ + kb0 + cs * 8, &vdst[(w * 16 + j * 8) * 64]);
        }
    };

    float l_lane[2] = {0.f, 0.f};
    floatx4 o_acc[2][4];
    #pragma unroll
    for (int g = 0; g < 2; ++g)
        #pragma unroll
        for (int dt = 0; dt < 4; ++dt) o_acc[g][dt] = (floatx4){0.f, 0.f, 0.f, 0.f};

    stage(0, kbuf[0], vbuf[0]);
    __syncthreads();

    for (int t = 0; t < nc; ++t) {
        const int cur = t & 1;
        if (t + 1 < nc) stage((t + 1) * 64, kbuf[cur ^ 1], vbuf[cur ^ 1]);
        const short* kb  = kbuf[cur];
        const short* vbl = vbuf[cur];
        const int kbase = t * 64;

        // K A-fragments (swizzled): A[m=key][k=d]
        short8 ka[4][2];
        #pragma unroll
        for (int nt = 0; nt < 4; ++nt) {
            const int row = nt * 16 + l15;
            ka[nt][0] = *(const short8*)&kb[row * 64 + ((quad    ) ^ (row & 7)) * 8];
            ka[nt][1] = *(const short8*)&kb[row * 64 + ((4 + quad) ^ (row & 7)) * 8];
        }
        // V fragments: lane map serves as A[m=d l15][k=key quad*8+j]
        short8 vf[2][4];
        #pragma unroll
        for (int dt = 0; dt < 4; ++dt) {
            const int row = dt * 16 + l15;
            vf[0][dt] = *(const short8*)&vbl[row * 64 + ((quad    ) ^ (row & 7)) * 8];
            vf[1][dt] = *(const short8*)&vbl[row * 64 + ((4 + quad) ^ (row & 7)) * 8];
        }
        // compacted mask (1 real / 0 pad) for this lane's keys
        float4 m4[4];
        #pragma unroll
        for (int nt = 0; nt < 4; ++nt)
            m4[nt] = *(const float4*)(mk + kbase + nt * 16 + quad * 4);

        #pragma unroll
        for (int g = 0; g < 2; ++g) {
            // S^T = K·Q^T : D[m=key][n=query]
            floatx4 st[4];
            #pragma unroll
            for (int nt = 0; nt < 4; ++nt) {
                floatx4 a = {0.f, 0.f, 0.f, 0.f};
                a = __builtin_amdgcn_mfma_f32_16x16x32_bf16(ka[nt][1], qa[g][1], a, 0, 0, 0);
                a = __builtin_amdgcn_mfma_f32_16x16x32_bf16(ka[nt][0], qa[g][0], a, 0, 0, 0);
                st[nt] = a;
            }
            // p = mask * exp2(s); P -> psh (swizzled, wave-private rows)
            const int prow = w * 32 + g * 16 + l15;
            float psum = 0.f;
            #pragma unroll
            for (int nt = 0; nt < 4; ++nt) {
                float p0 = m4[nt].x * __builtin_amdgcn_exp2f(st[nt][0]);
                float p1 = m4[nt].y * __builtin_amdgcn_exp2f(st[nt][1]);
                float p2 = m4[nt].z * __builtin_amdgcn_exp2f(st[nt][2]);
                float p3 = m4[nt].w * __builtin_amdgcn_exp2f(st[nt][3]);
                psum += (p0 + p1) + (p2 + p3);
                int2 pk = make_int2(f2bf_pk(p0, p1), f2bf_pk(p2, p3));
                const int c16 = (2 * nt + (quad >> 1)) ^ (prow & 7);
                *(int2*)&psh[prow * 64 + c16 * 8 + (quad & 1) * 4] = pk;
            }
            l_lane[g] += psum;
            // O^T += V^T·P^T (operand-swapped; same-wave psh write->read)
            #pragma unroll
            for (int kt = 0; kt < 2; ++kt) {
                short8 pa = *(const short8*)&psh[prow * 64 + ((kt * 4 + quad) ^ (prow & 7)) * 8];
                #pragma unroll
                for (int dt = 0; dt < 4; ++dt)
                    o_acc[g][dt] = __builtin_amdgcn_mfma_f32_16x16x32_bf16(vf[kt][dt], pa, o_acc[g][dt], 0, 0, 0);
            }
        }
        __syncthreads();   // next chunk staged + all waves done with this buffer
    }

    // epilogue: O^T layout => q=l15, d=dt*16+quad*4+i; float4 stores
    #pragma unroll
    for (int g = 0; g < 2; ++g) {
        float ls = l_lane[g];
        ls += __shfl_xor(ls, 16);
        ls += __shfl_xor(ls, 32);
        const float linv = 1.0f / ls;
        const int qr = qq * 128 + w * 32 + g * 16 + l15;
        float* orow = out + ((size_t)b * NQ_ + qr) * HD_ + h * D_;
        #pragma unroll
        for (int dt = 0; dt < 4; ++dt) {
            float4 v = make_float4(o_acc[g][dt][0] * linv, o_acc[g][dt][1] * linv,
                                   o_acc[g][dt][2] * linv, o_acc[g][dt][3] * linv);
            *(float4*)(orow + dt * 16 + quad * 4) = v;
        }
    }
}

extern "C" void kernel_launch(void* const* d_in, const int* in_sizes, int n_in,
                              void* d_out, int out_size, void* d_ws, size_t ws_size,
                              hipStream_t stream) {
    const float* query = (const float*)d_in[0];
    const float* key   = (const float*)d_in[1];
    const float* cmask = (const float*)d_in[2];
    const float* Wq    = (const float*)d_in[3];
    const float* bq    = (const float*)d_in[4];
    const float* Wk    = (const float*)d_in[5];
    const float* bk    = (const float*)d_in[6];
    const float* Wv    = (const float*)d_in[7];
    const float* bv    = (const float*)d_in[8];
    float* out = (float*)d_out;

    char* ws = (char*)d_ws;
    short* ks  = (short*)(ws);                           // 16 MB (B*H*NK*D bf16)
    short* vt  = (short*)(ws + (size_t)(16u << 20));     // 16 MB (B*H*D*NK bf16)
    char*  w32 = ws + (size_t)(32u << 20);
    short* wqt = (short*)(w32);                          // 128 KB each
    short* wkt = (short*)(w32 + 131072);
    short* wvt = (short*)(w32 + 131072 * 2);
    float* bqs = (float*)(w32 + 131072 * 3);             // 2 KB
    int*   idx = (int*)(w32 + 131072 * 3 + 4096);        // 64 KB (16*1024 int)
    float* cm2 = (float*)(w32 + 131072 * 3 + 4096 + 65536);  // 64 KB
    int*  npad = (int*)(w32 + 131072 * 3 + 4096 + 131072);   // 64 B

    const float qscale = 0.125f * 1.44269504f;    // 1/sqrt(64) * log2(e)
    prep_kernel<<<dim3(65), dim3(256), 0, stream>>>(
        Wq, Wk, Wv, wqt, wkt, wvt, bq, bqs, qscale, cmask, idx, cm2, npad);

    kvproj_kernel<<<dim3(256, 2), dim3(256), 0, stream>>>(
        key, wkt, wvt, bk, bv, ks, vt, idx, npad);

    attn_kernel<<<dim3(512), dim3(256), 0, stream>>>(
        query, ks, vt, cm2, wqt, bqs, npad, out);
}